// Round 4
// baseline (225.287 us; speedup 1.0000x reference)
//
#include <hip/hip_runtime.h>
#include <stdint.h>

// set attention: N=32, L=256, D=20, H=2, Dh=20, fp32 I/O.
// Out batch b: Q from x[b], K/V from y[(b&31)*32 + (b>>5)].
// R8: VALU-cut + intra-wave ILP on top of v7 (passed, 100us, 4 blk/CU).
//   - fp32->bf16 = round-half-up (u+0x8000)>>16; pairs packed by v_perm_b32
//     (builtin). Differs from RNE only on exact ties (2^-16) -> absmax ~same.
//   - V^T stores: packed ds_write_b64 (2 perm) instead of 4 scalar b16 writes.
//   - s0 loop unroll x2: 16 independent MFMA/softmax chains in flight.
//   - Structure/barriers byte-identical to v7 otherwise.

#define NSET 32
#define SEQL 256
#define DM   20
#define NH   2
#define DH   20

typedef __attribute__((ext_vector_type(8))) short short8;
typedef __attribute__((ext_vector_type(4))) short short4v;
typedef __attribute__((ext_vector_type(4))) float f32x4;

#define MFMA32(a, b, c) __builtin_amdgcn_mfma_f32_16x16x32_bf16((a), (b), (c), 0, 0, 0)

#if __has_builtin(__builtin_amdgcn_mfma_f32_16x16x16bf16_1k)
#define MFMA16(a, b, c) __builtin_amdgcn_mfma_f32_16x16x16bf16_1k((a), (b), (c), 0, 0, 0)
#elif __has_builtin(__builtin_amdgcn_mfma_f32_16x16x16_bf16)
#define MFMA16(a, b, c) __builtin_amdgcn_mfma_f32_16x16x16_bf16((a), (b), (c), 0, 0, 0)
#else
static __device__ __forceinline__ f32x4 MFMA16(short4v a, short4v b, f32x4 c) {
    asm volatile("s_nop 1\n\tv_mfma_f32_16x16x16_bf16 %0, %1, %2, %0\n\ts_nop 7"
                 : "+v"(c) : "v"(a), "v"(b));
    return c;
}
#endif

// fp32 -> bf16 bits, round-half-up-to-nearest (ties differ from RNE only): 2 VALU
__device__ __forceinline__ uint32_t bfhu(float f) {
    return (__float_as_uint(f) + 0x8000u) >> 16;
}
// two fp32 -> packed {bf16(hi),bf16(lo)}: 2 add + 1 v_perm_b32
__device__ __forceinline__ uint32_t packbf(float hi, float lo) {
    return __builtin_amdgcn_perm(__float_as_uint(hi) + 0x8000u,
                                 __float_as_uint(lo) + 0x8000u, 0x07060302u);
}
__device__ __forceinline__ float fexp2(float x) {
    float r;
    asm("v_exp_f32 %0, %1" : "=v"(r) : "v"(x));
    return r;
}

// predicated b128 A/B-frag load from row-major [rows][24] bf16 region
__device__ __forceinline__ short8 ldsA(const short* base, int row, int qd) {
    short8 f = {0, 0, 0, 0, 0, 0, 0, 0};
    if (qd < 3) f = *(const short8*)(base + row * 24 + qd * 8);
    return f;
}

// global fp32 row (20 floats, 16B-aligned) -> bf16 frag for k-quad qd
__device__ __forceinline__ short8 gfrag(const float* rowp, int qd) {
    short8 f = {0, 0, 0, 0, 0, 0, 0, 0};
    if (qd < 2) {
        float4 a = *(const float4*)(rowp + qd * 8);
        float4 b = *(const float4*)(rowp + qd * 8 + 4);
        *(uint2*)&f = make_uint2(packbf(a.y, a.x), packbf(a.w, a.z));
        *(((uint2*)&f) + 1) = make_uint2(packbf(b.y, b.x), packbf(b.w, b.z));
    } else if (qd == 2) {
        float4 a = *(const float4*)(rowp + 16);
        *(uint2*)&f = make_uint2(packbf(a.y, a.x), packbf(a.w, a.z));
    }
    return f;
}

__global__ __launch_bounds__(256, 4) void set_attn_v8(
    const float* __restrict__ x, const float* __restrict__ y,
    const float* __restrict__ wq, const float* __restrict__ wk,
    const float* __restrict__ wv, const float* __restrict__ wh,
    float* __restrict__ out)
{
    __shared__ __align__(16) short sK[SEQL * 24];     // per-head K, 12 KB
    __shared__ __align__(16) short sVt[20 * 264];     // per-head V^T [d][s], 10.3 KB
    __shared__ __align__(16) short sW[4 * 64 * 24];   // per-wave transpose scratch, 12 KB
    __shared__ float sL[256];                         // per-row softmax denom, 1 KB

    const int tid  = threadIdx.x;
    const int lane = tid & 63;
    const int w    = tid >> 6;
    const int c    = lane & 15;
    const int qd   = lane >> 4;
    const int b    = blockIdx.x;
    const int bi   = b >> 5, bj = b & 31;

    short* myW = sW + w * (64 * 24);

    // zero pad cols 20..23 (read by qd==2 frags); later writes never touch them
    *(uint2*)(sK + tid * 24 + 20) = make_uint2(0u, 0u);
    *(uint2*)(myW + lane * 24 + 20) = make_uint2(0u, 0u);

    const float QS = 0.22360679774997896f * 1.4426950408889634f;  // scale * log2(e)

    // ---- Q projection (both heads), barrier-synced scratch transpose ----
    short8 xf[4];
#pragma unroll
    for (int mt = 0; mt < 4; ++mt)
        xf[mt] = gfrag(x + ((size_t)b * SEQL + w * 64 + mt * 16 + c) * DM, qd);

    short8 qb[2][4];
#pragma unroll
    for (int h = 0; h < 2; ++h) {
        short8 wqf[2];
#pragma unroll
        for (int dt = 0; dt < 2; ++dt) {
            int n = dt * 16 + c;
            short8 f = {0,0,0,0,0,0,0,0};
            if (n < 20) {
#pragma unroll
                for (int j = 0; j < 8; ++j) {
                    int k = qd * 8 + j;
                    if (k < 20) f[j] = (short)bfhu(wq[k * 40 + h * 20 + n]);
                }
            }
            wqf[dt] = f;
        }
#pragma unroll
        for (int mt = 0; mt < 4; ++mt) {
#pragma unroll
            for (int dt = 0; dt < 2; ++dt) {
                f32x4 z = {0.f, 0.f, 0.f, 0.f};
                f32x4 qres = MFMA32(xf[mt], wqf[dt], z);
                int n = dt * 16 + c;
                if (n < 20) {
#pragma unroll
                    for (int reg = 0; reg < 4; ++reg)
                        myW[(mt * 16 + qd * 4 + reg) * 24 + n] =
                            (short)bfhu(qres[reg] * QS);
                }
            }
        }
        __syncthreads();   // Q writes (and pads, first iter) visible
#pragma unroll
        for (int mt = 0; mt < 4; ++mt) qb[h][mt] = ldsA(myW, mt * 16 + c, qd);
        __syncthreads();   // reads retired before scratch overwritten
    }

    // ---- K/V projection for head h into sK / sVt ----
    auto project_kv = [&](int h) {
        short8 wkf[2], wvf[2];
#pragma unroll
        for (int dt = 0; dt < 2; ++dt) {
            int n = dt * 16 + c;
            short8 fk = {0,0,0,0,0,0,0,0}, fv = fk;
            if (n < 20) {
#pragma unroll
                for (int j = 0; j < 8; ++j) {
                    int k = qd * 8 + j;
                    if (k < 20) {
                        fk[j] = (short)bfhu(wk[k * 40 + h * 20 + n]);
                        fv[j] = (short)bfhu(wv[k * 40 + h * 20 + n]);
                    }
                }
            }
            wkf[dt] = fk; wvf[dt] = fv;
        }
#pragma unroll
        for (int mt = 0; mt < 4; ++mt) {
            int rbase = w * 64 + mt * 16;
            short8 yf = gfrag(y + ((size_t)(bj * NSET + bi) * SEQL + rbase + c) * DM, qd);
#pragma unroll
            for (int dt = 0; dt < 2; ++dt) {
                f32x4 z = {0.f, 0.f, 0.f, 0.f};
                f32x4 kres = MFMA32(yf, wkf[dt], z);
                f32x4 vres = MFMA32(yf, wvf[dt], z);
                int n = dt * 16 + c;
                if (n < 20) {
#pragma unroll
                    for (int reg = 0; reg < 4; ++reg)
                        sK[(rbase + qd * 4 + reg) * 24 + n] = (short)bfhu(kres[reg]);
                    // 4 consecutive s-rows -> one packed b64 store into V^T
                    uint2 pv = make_uint2(packbf(vres[1], vres[0]),
                                          packbf(vres[3], vres[2]));
                    *(uint2*)(sVt + n * 264 + rbase + qd * 4) = pv;
                }
            }
        }
    };

    project_kv(0);
    __syncthreads();   // B1: sK/sVt head0 ready

    f32x4 outacc[4][2];
#pragma unroll
    for (int mt = 0; mt < 4; ++mt)
#pragma unroll
        for (int dt = 0; dt < 2; ++dt) outacc[mt][dt] = (f32x4){0.f, 0.f, 0.f, 0.f};

#pragma unroll
    for (int h = 0; h < NH; ++h) {
        f32x4 oacc[4][2];
#pragma unroll
        for (int mt = 0; mt < 4; ++mt)
#pragma unroll
            for (int dt = 0; dt < 2; ++dt) oacc[mt][dt] = (f32x4){0.f, 0.f, 0.f, 0.f};
        float ls0 = 0.f, ls1 = 0.f, ls2 = 0.f, ls3 = 0.f;

#pragma unroll 2
        for (int s0 = 0; s0 < SEQL; s0 += 32) {
            short8 kf0 = ldsA(sK, s0 + c, qd);
            short8 kf1 = ldsA(sK, s0 + 16 + c, qd);
            short4v vb[2][2];
#pragma unroll
            for (int dt = 0; dt < 2; ++dt) {
                int d = dt * 16 + c;
#pragma unroll
                for (int st = 0; st < 2; ++st) {
                    uint2 u = make_uint2(0u, 0u);
                    if (d < 20)
                        u = *(const uint2*)(sVt + d * 264 + s0 + st * 16 + qd * 4);
                    short4v t; *(uint2*)&t = u;
                    vb[st][dt] = t;
                }
            }
#pragma unroll
            for (int mt = 0; mt < 4; ++mt) {
#pragma unroll
                for (int st = 0; st < 2; ++st) {
                    f32x4 z = {0.f, 0.f, 0.f, 0.f};
                    f32x4 sacc = MFMA32((st == 0 ? kf0 : kf1), qb[h][mt], z);
                    float p0, p1, p2, p3;
                    {
                        float v0 = sacc[0], v1 = sacc[1], v2 = sacc[2], v3 = sacc[3];
                        p0 = (v0 != 0.f) ? fexp2(v0) : 0.f;   // zero-logit mask
                        p1 = (v1 != 0.f) ? fexp2(v1) : 0.f;
                        p2 = (v2 != 0.f) ? fexp2(v2) : 0.f;
                        p3 = (v3 != 0.f) ? fexp2(v3) : 0.f;
                    }
                    float lsum = (p0 + p1) + (p2 + p3);
                    if (mt == 0) ls0 += lsum;
                    else if (mt == 1) ls1 += lsum;
                    else if (mt == 2) ls2 += lsum;
                    else ls3 += lsum;
                    short4v pf;
                    *(uint2*)&pf = make_uint2(packbf(p1, p0), packbf(p3, p2));
                    oacc[mt][0] = MFMA16(pf, vb[st][0], oacc[mt][0]);
                    oacc[mt][1] = MFMA16(pf, vb[st][1], oacc[mt][1]);
                }
            }
        }

        // ---- softmax denominators: reduce over qd groups, broadcast via sL ----
        ls0 += __shfl_xor(ls0, 16, 64); ls0 += __shfl_xor(ls0, 32, 64);
        ls1 += __shfl_xor(ls1, 16, 64); ls1 += __shfl_xor(ls1, 32, 64);
        ls2 += __shfl_xor(ls2, 16, 64); ls2 += __shfl_xor(ls2, 32, 64);
        ls3 += __shfl_xor(ls3, 16, 64); ls3 += __shfl_xor(ls3, 32, 64);
        float sel = ls0;
        if (qd == 1) sel = ls1;
        if (qd == 2) sel = ls2;
        if (qd == 3) sel = ls3;
        sL[w * 64 + lane] = sel;   // sL[w*64 + i] = denom of wave-local row i
        __syncthreads();           // sL visible

        // ---- normalize O into wave scratch ----
        short8 whf[2];
#pragma unroll
        for (int dt = 0; dt < 2; ++dt) {
            int n = dt * 16 + c;
            short8 f = {0,0,0,0,0,0,0,0};
            if (n < 20) {
#pragma unroll
                for (int j = 0; j < 8; ++j) {
                    int k = qd * 8 + j;
                    if (k < 20) f[j] = (short)bfhu(wh[(h * 20 + k) * 20 + n]);
                }
            }
            whf[dt] = f;
        }
#pragma unroll
        for (int mt = 0; mt < 4; ++mt) {
            float inv[4];
#pragma unroll
            for (int reg = 0; reg < 4; ++reg)
                inv[reg] = 1.f / (sL[w * 64 + mt * 16 + qd * 4 + reg] + 1e-10f);
#pragma unroll
            for (int dt = 0; dt < 2; ++dt) {
                int n = dt * 16 + c;
                if (n < 20) {
#pragma unroll
                    for (int reg = 0; reg < 4; ++reg)
                        myW[(mt * 16 + qd * 4 + reg) * 24 + n] =
                            (short)bfhu(oacc[mt][dt][reg] * inv[reg]);
                }
            }
        }
        __syncthreads();   // O writes visible before transposed read

        // ---- out-projection: outacc += O_h * WH[h*20:(h+1)*20, :] ----
#pragma unroll
        for (int mt = 0; mt < 4; ++mt) {
            short8 of = ldsA(myW, mt * 16 + c, qd);
            outacc[mt][0] = MFMA32(of, whf[0], outacc[mt][0]);
            outacc[mt][1] = MFMA32(of, whf[1], outacc[mt][1]);
        }

        if (h == 0) {
            __syncthreads();     // B2: all reads of sK/sVt head0 + myW done
            project_kv(1);
            __syncthreads();     // B3: sK/sVt head1 ready
        }
    }

    // ---- store fp32 output ----
    float* ob = out + (size_t)b * (SEQL * DH);
#pragma unroll
    for (int mt = 0; mt < 4; ++mt)
#pragma unroll
        for (int dt = 0; dt < 2; ++dt) {
            int n = dt * 16 + c;
            if (n < 20) {
#pragma unroll
                for (int reg = 0; reg < 4; ++reg) {
                    int row = w * 64 + mt * 16 + qd * 4 + reg;
                    ob[row * 20 + n] = outacc[mt][dt][reg];
                }
            }
        }
}

extern "C" void kernel_launch(void* const* d_in, const int* in_sizes, int n_in,
                              void* d_out, int out_size, void* d_ws, size_t ws_size,
                              hipStream_t stream) {
    const float* x  = (const float*)d_in[0];
    const float* y  = (const float*)d_in[1];
    const float* wq = (const float*)d_in[2];
    const float* wk = (const float*)d_in[3];
    const float* wv = (const float*)d_in[4];
    const float* wh = (const float*)d_in[5];
    float* out = (float*)d_out;

    set_attn_v8<<<dim3(NSET * NSET), dim3(SEQL), 0, stream>>>(x, y, wq, wk, wv, wh, out);
}

// Round 5
// 165.527 us; speedup vs baseline: 1.3610x; 1.3610x over previous
//
#include <hip/hip_runtime.h>
#include <stdint.h>

// set attention: N=32, L=256, D=20, H=2, Dh=20, fp32 I/O.
// Out batch b: Q from x[b], K/V from y[(b&31)*32 + (b>>5)].
// R9: spill elimination. Evidence: WRITE_SIZE 20.5MB(R0,256vgpr budget) vs
// 66MB(v7,128 budget) vs 122MB(v8,unroll2) with identical store code -> v7/v8
// spill in the s0 loop. Fix: __launch_bounds__(256,3) -> 170-reg budget,
// 3 blocks/CU (12 waves/CU vs R0's 8), zero spills.
//   - Conversions: round-half-up (u+0x8000)>>16 + v_perm_b32 pack (v8-proven).
//   - NO unroll-2 (spill amplifier). No v_cvt_pk asm (v5/v6 NaN).
//   - Structure/barriers identical to v7.

#define NSET 32
#define SEQL 256
#define DM   20
#define NH   2
#define DH   20

typedef __attribute__((ext_vector_type(8))) short short8;
typedef __attribute__((ext_vector_type(4))) short short4v;
typedef __attribute__((ext_vector_type(4))) float f32x4;

#define MFMA32(a, b, c) __builtin_amdgcn_mfma_f32_16x16x32_bf16((a), (b), (c), 0, 0, 0)

#if __has_builtin(__builtin_amdgcn_mfma_f32_16x16x16bf16_1k)
#define MFMA16(a, b, c) __builtin_amdgcn_mfma_f32_16x16x16bf16_1k((a), (b), (c), 0, 0, 0)
#elif __has_builtin(__builtin_amdgcn_mfma_f32_16x16x16_bf16)
#define MFMA16(a, b, c) __builtin_amdgcn_mfma_f32_16x16x16_bf16((a), (b), (c), 0, 0, 0)
#else
static __device__ __forceinline__ f32x4 MFMA16(short4v a, short4v b, f32x4 c) {
    asm volatile("s_nop 1\n\tv_mfma_f32_16x16x16_bf16 %0, %1, %2, %0\n\ts_nop 7"
                 : "+v"(c) : "v"(a), "v"(b));
    return c;
}
#endif

// fp32 -> bf16 bits, round-half-up (differs from RNE only on exact ties)
__device__ __forceinline__ uint32_t bfhu(float f) {
    return (__float_as_uint(f) + 0x8000u) >> 16;
}
// two fp32 -> packed {bf16(hi),bf16(lo)}: 2 add + 1 v_perm_b32 (v8-proven)
__device__ __forceinline__ uint32_t packbf(float hi, float lo) {
    return __builtin_amdgcn_perm(__float_as_uint(hi) + 0x8000u,
                                 __float_as_uint(lo) + 0x8000u, 0x07060302u);
}
__device__ __forceinline__ float fexp2(float x) {
    float r;
    asm("v_exp_f32 %0, %1" : "=v"(r) : "v"(x));
    return r;
}

// predicated b128 A/B-frag load from row-major [rows][24] bf16 region
__device__ __forceinline__ short8 ldsA(const short* base, int row, int qd) {
    short8 f = {0, 0, 0, 0, 0, 0, 0, 0};
    if (qd < 3) f = *(const short8*)(base + row * 24 + qd * 8);
    return f;
}

// global fp32 row (20 floats, 16B-aligned) -> bf16 frag for k-quad qd
__device__ __forceinline__ short8 gfrag(const float* rowp, int qd) {
    short8 f = {0, 0, 0, 0, 0, 0, 0, 0};
    if (qd < 2) {
        float4 a = *(const float4*)(rowp + qd * 8);
        float4 b = *(const float4*)(rowp + qd * 8 + 4);
        f[0] = (short)bfhu(a.x); f[1] = (short)bfhu(a.y);
        f[2] = (short)bfhu(a.z); f[3] = (short)bfhu(a.w);
        f[4] = (short)bfhu(b.x); f[5] = (short)bfhu(b.y);
        f[6] = (short)bfhu(b.z); f[7] = (short)bfhu(b.w);
    } else if (qd == 2) {
        float4 a = *(const float4*)(rowp + 16);
        f[0] = (short)bfhu(a.x); f[1] = (short)bfhu(a.y);
        f[2] = (short)bfhu(a.z); f[3] = (short)bfhu(a.w);
    }
    return f;
}

__global__ __launch_bounds__(256, 3) void set_attn_v9(
    const float* __restrict__ x, const float* __restrict__ y,
    const float* __restrict__ wq, const float* __restrict__ wk,
    const float* __restrict__ wv, const float* __restrict__ wh,
    float* __restrict__ out)
{
    __shared__ __align__(16) short sK[SEQL * 24];     // per-head K, 12 KB
    __shared__ __align__(16) short sVt[20 * 264];     // per-head V^T [d][s], 10.3 KB
    __shared__ __align__(16) short sW[4 * 64 * 24];   // per-wave transpose scratch, 12 KB
    __shared__ float sL[256];                         // per-row softmax denom, 1 KB

    const int tid  = threadIdx.x;
    const int lane = tid & 63;
    const int w    = tid >> 6;
    const int c    = lane & 15;
    const int qd   = lane >> 4;
    const int b    = blockIdx.x;
    const int bi   = b >> 5, bj = b & 31;

    short* myW = sW + w * (64 * 24);

    // zero pad cols 20..23 (read by qd==2 frags); later writes never touch them
    *(uint2*)(sK + tid * 24 + 20) = make_uint2(0u, 0u);
    *(uint2*)(myW + lane * 24 + 20) = make_uint2(0u, 0u);

    const float QS = 0.22360679774997896f * 1.4426950408889634f;  // scale * log2(e)

    // ---- Q projection (both heads), barrier-synced scratch transpose ----
    short8 xf[4];
#pragma unroll
    for (int mt = 0; mt < 4; ++mt)
        xf[mt] = gfrag(x + ((size_t)b * SEQL + w * 64 + mt * 16 + c) * DM, qd);

    short8 qb[2][4];
#pragma unroll
    for (int h = 0; h < 2; ++h) {
        short8 wqf[2];
#pragma unroll
        for (int dt = 0; dt < 2; ++dt) {
            int n = dt * 16 + c;
            short8 f = {0,0,0,0,0,0,0,0};
            if (n < 20) {
#pragma unroll
                for (int j = 0; j < 8; ++j) {
                    int k = qd * 8 + j;
                    if (k < 20) f[j] = (short)bfhu(wq[k * 40 + h * 20 + n]);
                }
            }
            wqf[dt] = f;
        }
#pragma unroll
        for (int mt = 0; mt < 4; ++mt) {
#pragma unroll
            for (int dt = 0; dt < 2; ++dt) {
                f32x4 z = {0.f, 0.f, 0.f, 0.f};
                f32x4 qres = MFMA32(xf[mt], wqf[dt], z);
                int n = dt * 16 + c;
                if (n < 20) {
#pragma unroll
                    for (int reg = 0; reg < 4; ++reg)
                        myW[(mt * 16 + qd * 4 + reg) * 24 + n] =
                            (short)bfhu(qres[reg] * QS);
                }
            }
        }
        __syncthreads();   // Q writes (and pads, first iter) visible
#pragma unroll
        for (int mt = 0; mt < 4; ++mt) qb[h][mt] = ldsA(myW, mt * 16 + c, qd);
        __syncthreads();   // reads retired before scratch overwritten
    }

    // ---- K/V projection for head h into sK / sVt ----
    auto project_kv = [&](int h) {
        short8 wkf[2], wvf[2];
#pragma unroll
        for (int dt = 0; dt < 2; ++dt) {
            int n = dt * 16 + c;
            short8 fk = {0,0,0,0,0,0,0,0}, fv = fk;
            if (n < 20) {
#pragma unroll
                for (int j = 0; j < 8; ++j) {
                    int k = qd * 8 + j;
                    if (k < 20) {
                        fk[j] = (short)bfhu(wk[k * 40 + h * 20 + n]);
                        fv[j] = (short)bfhu(wv[k * 40 + h * 20 + n]);
                    }
                }
            }
            wkf[dt] = fk; wvf[dt] = fv;
        }
#pragma unroll
        for (int mt = 0; mt < 4; ++mt) {
            int rbase = w * 64 + mt * 16;
            short8 yf = gfrag(y + ((size_t)(bj * NSET + bi) * SEQL + rbase + c) * DM, qd);
#pragma unroll
            for (int dt = 0; dt < 2; ++dt) {
                f32x4 z = {0.f, 0.f, 0.f, 0.f};
                f32x4 kres = MFMA32(yf, wkf[dt], z);
                f32x4 vres = MFMA32(yf, wvf[dt], z);
                int n = dt * 16 + c;
                if (n < 20) {
#pragma unroll
                    for (int reg = 0; reg < 4; ++reg)
                        sK[(rbase + qd * 4 + reg) * 24 + n] = (short)bfhu(kres[reg]);
                    // 4 consecutive s-rows -> one packed b64 store into V^T
                    uint2 pv = make_uint2(packbf(vres[1], vres[0]),
                                          packbf(vres[3], vres[2]));
                    *(uint2*)(sVt + n * 264 + rbase + qd * 4) = pv;
                }
            }
        }
    };

    project_kv(0);
    __syncthreads();   // B1: sK/sVt head0 ready

    f32x4 outacc[4][2];
#pragma unroll
    for (int mt = 0; mt < 4; ++mt)
#pragma unroll
        for (int dt = 0; dt < 2; ++dt) outacc[mt][dt] = (f32x4){0.f, 0.f, 0.f, 0.f};

#pragma unroll
    for (int h = 0; h < NH; ++h) {
        f32x4 oacc[4][2];
#pragma unroll
        for (int mt = 0; mt < 4; ++mt)
#pragma unroll
            for (int dt = 0; dt < 2; ++dt) oacc[mt][dt] = (f32x4){0.f, 0.f, 0.f, 0.f};
        float ls0 = 0.f, ls1 = 0.f, ls2 = 0.f, ls3 = 0.f;

        for (int s0 = 0; s0 < SEQL; s0 += 32) {
            short8 kf0 = ldsA(sK, s0 + c, qd);
            short8 kf1 = ldsA(sK, s0 + 16 + c, qd);
            short4v vb[2][2];
#pragma unroll
            for (int dt = 0; dt < 2; ++dt) {
                int d = dt * 16 + c;
#pragma unroll
                for (int st = 0; st < 2; ++st) {
                    uint2 u = make_uint2(0u, 0u);
                    if (d < 20)
                        u = *(const uint2*)(sVt + d * 264 + s0 + st * 16 + qd * 4);
                    short4v t; *(uint2*)&t = u;
                    vb[st][dt] = t;
                }
            }
#pragma unroll
            for (int mt = 0; mt < 4; ++mt) {
#pragma unroll
                for (int st = 0; st < 2; ++st) {
                    f32x4 z = {0.f, 0.f, 0.f, 0.f};
                    f32x4 sacc = MFMA32((st == 0 ? kf0 : kf1), qb[h][mt], z);
                    float p0, p1, p2, p3;
                    {
                        float v0 = sacc[0], v1 = sacc[1], v2 = sacc[2], v3 = sacc[3];
                        p0 = (v0 != 0.f) ? fexp2(v0) : 0.f;   // zero-logit mask
                        p1 = (v1 != 0.f) ? fexp2(v1) : 0.f;
                        p2 = (v2 != 0.f) ? fexp2(v2) : 0.f;
                        p3 = (v3 != 0.f) ? fexp2(v3) : 0.f;
                    }
                    float lsum = (p0 + p1) + (p2 + p3);
                    if (mt == 0) ls0 += lsum;
                    else if (mt == 1) ls1 += lsum;
                    else if (mt == 2) ls2 += lsum;
                    else ls3 += lsum;
                    short4v pf;
                    *(uint2*)&pf = make_uint2(packbf(p1, p0), packbf(p3, p2));
                    oacc[mt][0] = MFMA16(pf, vb[st][0], oacc[mt][0]);
                    oacc[mt][1] = MFMA16(pf, vb[st][1], oacc[mt][1]);
                }
            }
        }

        // ---- softmax denominators: reduce over qd groups, broadcast via sL ----
        ls0 += __shfl_xor(ls0, 16, 64); ls0 += __shfl_xor(ls0, 32, 64);
        ls1 += __shfl_xor(ls1, 16, 64); ls1 += __shfl_xor(ls1, 32, 64);
        ls2 += __shfl_xor(ls2, 16, 64); ls2 += __shfl_xor(ls2, 32, 64);
        ls3 += __shfl_xor(ls3, 16, 64); ls3 += __shfl_xor(ls3, 32, 64);
        float sel = ls0;
        if (qd == 1) sel = ls1;
        if (qd == 2) sel = ls2;
        if (qd == 3) sel = ls3;
        sL[w * 64 + lane] = sel;   // sL[w*64 + i] = denom of wave-local row i
        __syncthreads();           // sL visible

        // ---- normalize O into wave scratch ----
        short8 whf[2];
#pragma unroll
        for (int dt = 0; dt < 2; ++dt) {
            int n = dt * 16 + c;
            short8 f = {0,0,0,0,0,0,0,0};
            if (n < 20) {
#pragma unroll
                for (int j = 0; j < 8; ++j) {
                    int k = qd * 8 + j;
                    if (k < 20) f[j] = (short)bfhu(wh[(h * 20 + k) * 20 + n]);
                }
            }
            whf[dt] = f;
        }
#pragma unroll
        for (int mt = 0; mt < 4; ++mt) {
            float inv[4];
#pragma unroll
            for (int reg = 0; reg < 4; ++reg)
                inv[reg] = 1.f / (sL[w * 64 + mt * 16 + qd * 4 + reg] + 1e-10f);
#pragma unroll
            for (int dt = 0; dt < 2; ++dt) {
                int n = dt * 16 + c;
                if (n < 20) {
#pragma unroll
                    for (int reg = 0; reg < 4; ++reg)
                        myW[(mt * 16 + qd * 4 + reg) * 24 + n] =
                            (short)bfhu(oacc[mt][dt][reg] * inv[reg]);
                }
            }
        }
        __syncthreads();   // O writes visible before transposed read

        // ---- out-projection: outacc += O_h * WH[h*20:(h+1)*20, :] ----
#pragma unroll
        for (int mt = 0; mt < 4; ++mt) {
            short8 of = ldsA(myW, mt * 16 + c, qd);
            outacc[mt][0] = MFMA32(of, whf[0], outacc[mt][0]);
            outacc[mt][1] = MFMA32(of, whf[1], outacc[mt][1]);
        }

        if (h == 0) {
            __syncthreads();     // B2: all reads of sK/sVt head0 + myW done
            project_kv(1);
            __syncthreads();     // B3: sK/sVt head1 ready
        }
    }

    // ---- store fp32 output ----
    float* ob = out + (size_t)b * (SEQL * DH);
#pragma unroll
    for (int mt = 0; mt < 4; ++mt)
#pragma unroll
        for (int dt = 0; dt < 2; ++dt) {
            int n = dt * 16 + c;
            if (n < 20) {
#pragma unroll
                for (int reg = 0; reg < 4; ++reg) {
                    int row = w * 64 + mt * 16 + qd * 4 + reg;
                    ob[row * 20 + n] = outacc[mt][dt][reg];
                }
            }
        }
}

extern "C" void kernel_launch(void* const* d_in, const int* in_sizes, int n_in,
                              void* d_out, int out_size, void* d_ws, size_t ws_size,
                              hipStream_t stream) {
    const float* x  = (const float*)d_in[0];
    const float* y  = (const float*)d_in[1];
    const float* wq = (const float*)d_in[2];
    const float* wk = (const float*)d_in[3];
    const float* wv = (const float*)d_in[4];
    const float* wh = (const float*)d_in[5];
    float* out = (float*)d_out;

    set_attn_v9<<<dim3(NSET * NSET), dim3(SEQL), 0, stream>>>(x, y, wq, wk, wv, wh, out);
}

// Round 6
// 142.820 us; speedup vs baseline: 1.5774x; 1.1590x over previous
//
#include <hip/hip_runtime.h>
#include <stdint.h>

// set attention: N=32, L=256, D=20, H=2, Dh=20, fp32 I/O.
// Out batch b: Q from x[b], K/V from y[(b&31)*32 + (b>>5)].
// R10: heads parallel across waves (512-thr block, 8 waves: w<4 head0, w>=4 head1).
// Evidence: ~100us invariant vs occupancy/spills; all pipes <50% busy -> per-block
// serial phase chain (14 barrier phases, 2 sequential s0 passes) is the sink.
// This halves the chain: 6 barriers, one s0 pass per wave.
//   - All arithmetic primitives verbatim from v9 (passed, absmax 0.0332).
//   - Head partials combined via f32 LDS overlay on dead sK region.
//   - LDS 72.3 KB -> 2 blocks/CU (16 waves). __launch_bounds__(512,4) = 128-reg budget.

#define NSET 32
#define SEQL 256
#define DM   20
#define NH   2
#define DH   20

typedef __attribute__((ext_vector_type(8))) short short8;
typedef __attribute__((ext_vector_type(4))) short short4v;
typedef __attribute__((ext_vector_type(4))) float f32x4;

#define MFMA32(a, b, c) __builtin_amdgcn_mfma_f32_16x16x32_bf16((a), (b), (c), 0, 0, 0)

#if __has_builtin(__builtin_amdgcn_mfma_f32_16x16x16bf16_1k)
#define MFMA16(a, b, c) __builtin_amdgcn_mfma_f32_16x16x16bf16_1k((a), (b), (c), 0, 0, 0)
#elif __has_builtin(__builtin_amdgcn_mfma_f32_16x16x16_bf16)
#define MFMA16(a, b, c) __builtin_amdgcn_mfma_f32_16x16x16_bf16((a), (b), (c), 0, 0, 0)
#else
static __device__ __forceinline__ f32x4 MFMA16(short4v a, short4v b, f32x4 c) {
    asm volatile("s_nop 1\n\tv_mfma_f32_16x16x16_bf16 %0, %1, %2, %0\n\ts_nop 7"
                 : "+v"(c) : "v"(a), "v"(b));
    return c;
}
#endif

// fp32 -> bf16 bits, round-half-up (differs from RNE only on exact ties)
__device__ __forceinline__ uint32_t bfhu(float f) {
    return (__float_as_uint(f) + 0x8000u) >> 16;
}
// two fp32 -> packed {bf16(hi),bf16(lo)}: 2 add + 1 v_perm_b32 (v8/v9-proven)
__device__ __forceinline__ uint32_t packbf(float hi, float lo) {
    return __builtin_amdgcn_perm(__float_as_uint(hi) + 0x8000u,
                                 __float_as_uint(lo) + 0x8000u, 0x07060302u);
}
__device__ __forceinline__ float fexp2(float x) {
    float r;
    asm("v_exp_f32 %0, %1" : "=v"(r) : "v"(x));
    return r;
}

// predicated b128 A/B-frag load from row-major [rows][24] bf16 region
__device__ __forceinline__ short8 ldsA(const short* base, int row, int qd) {
    short8 f = {0, 0, 0, 0, 0, 0, 0, 0};
    if (qd < 3) f = *(const short8*)(base + row * 24 + qd * 8);
    return f;
}

// global fp32 row (20 floats, 16B-aligned) -> bf16 frag for k-quad qd
__device__ __forceinline__ short8 gfrag(const float* rowp, int qd) {
    short8 f = {0, 0, 0, 0, 0, 0, 0, 0};
    if (qd < 2) {
        float4 a = *(const float4*)(rowp + qd * 8);
        float4 b = *(const float4*)(rowp + qd * 8 + 4);
        f[0] = (short)bfhu(a.x); f[1] = (short)bfhu(a.y);
        f[2] = (short)bfhu(a.z); f[3] = (short)bfhu(a.w);
        f[4] = (short)bfhu(b.x); f[5] = (short)bfhu(b.y);
        f[6] = (short)bfhu(b.z); f[7] = (short)bfhu(b.w);
    } else if (qd == 2) {
        float4 a = *(const float4*)(rowp + 16);
        f[0] = (short)bfhu(a.x); f[1] = (short)bfhu(a.y);
        f[2] = (short)bfhu(a.z); f[3] = (short)bfhu(a.w);
    }
    return f;
}

// LDS layout (72,320 B total):
//   [     0, 24576)  sKb : bf16 K, [2 heads][256 rows][24]      (overlaid by sOut in epilogue)
//   [ 24576, 45696)  sVtb: bf16 V^T, [2 heads][20 d][264 s]
//   [ 45696, 70272)  sWb : bf16 per-wave scratch, [8 waves][64 rows][24]
//   [ 70272, 72320)  sL  : f32 [512] per-row softmax denom
#define SMEM_BYTES 72320

__global__ __launch_bounds__(512, 4) void set_attn_v10(
    const float* __restrict__ x, const float* __restrict__ y,
    const float* __restrict__ wq, const float* __restrict__ wk,
    const float* __restrict__ wv, const float* __restrict__ wh,
    float* __restrict__ out)
{
    __shared__ __align__(16) char smem[SMEM_BYTES];
    short* sKb  = (short*)smem;
    short* sVtb = (short*)(smem + 24576);
    short* sWb  = (short*)(smem + 45696);
    float* sL   = (float*)(smem + 70272);
    float* sOut = (float*)smem;            // overlay on sKb: [256][20] f32, epilogue only

    const int tid     = threadIdx.x;
    const int lane    = tid & 63;
    const int w       = tid >> 6;          // 0..7
    const int c       = lane & 15;
    const int qd      = lane >> 4;
    const int head    = w >> 2;            // 0 or 1
    const int rowbase = (w & 3) * 64;      // this wave's 64 rows
    const int b       = blockIdx.x;
    const int bi      = b >> 5, bj = b & 31;

    short* myW = sWb + w * (64 * 24);
    short* sK  = sKb + head * (SEQL * 24);
    short* sVt = sVtb + head * (20 * 264);

    // zero pad cols 20..23: sK rows 0..511 (both heads) via tid; myW own rows
    *(uint2*)(sKb + tid * 24 + 20) = make_uint2(0u, 0u);
    *(uint2*)(myW + lane * 24 + 20) = make_uint2(0u, 0u);

    const float QS = 0.22360679774997896f * 1.4426950408889634f;  // scale * log2(e)

    // ================= Phase 1: all projections for OWN head, OWN 64 rows ======
    // global loads batched: x rows, y rows, WQ/WK/WV gathers -> MFMA -> LDS writes
    short8 xf[4];
#pragma unroll
    for (int mt = 0; mt < 4; ++mt)
        xf[mt] = gfrag(x + ((size_t)b * SEQL + rowbase + mt * 16 + c) * DM, qd);

    short8 wqf[2], wkf[2], wvf[2];
#pragma unroll
    for (int dt = 0; dt < 2; ++dt) {
        int n = dt * 16 + c;
        short8 fq = {0,0,0,0,0,0,0,0}, fk = fq, fv = fq;
        if (n < 20) {
#pragma unroll
            for (int j = 0; j < 8; ++j) {
                int k = qd * 8 + j;
                if (k < 20) {
                    fq[j] = (short)bfhu(wq[k * 40 + head * 20 + n]);
                    fk[j] = (short)bfhu(wk[k * 40 + head * 20 + n]);
                    fv[j] = (short)bfhu(wv[k * 40 + head * 20 + n]);
                }
            }
        }
        wqf[dt] = fq; wkf[dt] = fk; wvf[dt] = fv;
    }

#pragma unroll
    for (int mt = 0; mt < 4; ++mt) {
        int rb = rowbase + mt * 16;        // local row in [0,256)
        short8 yf = gfrag(y + ((size_t)(bj * NSET + bi) * SEQL + rb + c) * DM, qd);
#pragma unroll
        for (int dt = 0; dt < 2; ++dt) {
            f32x4 z = {0.f, 0.f, 0.f, 0.f};
            f32x4 kres = MFMA32(yf, wkf[dt], z);
            f32x4 vres = MFMA32(yf, wvf[dt], z);
            f32x4 qres = MFMA32(xf[mt], wqf[dt], z);
            int n = dt * 16 + c;
            if (n < 20) {
#pragma unroll
                for (int reg = 0; reg < 4; ++reg) {
                    sK[(rb + qd * 4 + reg) * 24 + n] = (short)bfhu(kres[reg]);
                    myW[(mt * 16 + qd * 4 + reg) * 24 + n] =
                        (short)bfhu(qres[reg] * QS);
                }
                // 4 consecutive s-rows -> one packed b64 store into V^T
                uint2 pv = make_uint2(packbf(vres[1], vres[0]),
                                      packbf(vres[3], vres[2]));
                *(uint2*)(sVt + n * 264 + rb + qd * 4) = pv;
            }
        }
    }
    __syncthreads();   // BAR1: sK/sVt (own head quad) + myW + pads ready

    // ================= Phase 2: Q frags, s0 loop (ONE head), denominators ======
    short8 qb[4];
#pragma unroll
    for (int mt = 0; mt < 4; ++mt) qb[mt] = ldsA(myW, mt * 16 + c, qd);

    f32x4 oacc[4][2];
#pragma unroll
    for (int mt = 0; mt < 4; ++mt)
#pragma unroll
        for (int dt = 0; dt < 2; ++dt) oacc[mt][dt] = (f32x4){0.f, 0.f, 0.f, 0.f};
    float ls0 = 0.f, ls1 = 0.f, ls2 = 0.f, ls3 = 0.f;

    for (int s0 = 0; s0 < SEQL; s0 += 32) {
        short8 kf0 = ldsA(sK, s0 + c, qd);
        short8 kf1 = ldsA(sK, s0 + 16 + c, qd);
        short4v vb[2][2];
#pragma unroll
        for (int dt = 0; dt < 2; ++dt) {
            int d = dt * 16 + c;
#pragma unroll
            for (int st = 0; st < 2; ++st) {
                uint2 u = make_uint2(0u, 0u);
                if (d < 20)
                    u = *(const uint2*)(sVt + d * 264 + s0 + st * 16 + qd * 4);
                short4v t; *(uint2*)&t = u;
                vb[st][dt] = t;
            }
        }
#pragma unroll
        for (int mt = 0; mt < 4; ++mt) {
#pragma unroll
            for (int st = 0; st < 2; ++st) {
                f32x4 z = {0.f, 0.f, 0.f, 0.f};
                f32x4 sacc = MFMA32((st == 0 ? kf0 : kf1), qb[mt], z);
                float p0, p1, p2, p3;
                {
                    float v0 = sacc[0], v1 = sacc[1], v2 = sacc[2], v3 = sacc[3];
                    p0 = (v0 != 0.f) ? fexp2(v0) : 0.f;   // zero-logit mask
                    p1 = (v1 != 0.f) ? fexp2(v1) : 0.f;
                    p2 = (v2 != 0.f) ? fexp2(v2) : 0.f;
                    p3 = (v3 != 0.f) ? fexp2(v3) : 0.f;
                }
                float lsum = (p0 + p1) + (p2 + p3);
                if (mt == 0) ls0 += lsum;
                else if (mt == 1) ls1 += lsum;
                else if (mt == 2) ls2 += lsum;
                else ls3 += lsum;
                short4v pf;
                *(uint2*)&pf = make_uint2(packbf(p1, p0), packbf(p3, p2));
                oacc[mt][0] = MFMA16(pf, vb[st][0], oacc[mt][0]);
                oacc[mt][1] = MFMA16(pf, vb[st][1], oacc[mt][1]);
            }
        }
    }

    // softmax denominators: reduce over qd groups, broadcast via sL (v9-exact)
    ls0 += __shfl_xor(ls0, 16, 64); ls0 += __shfl_xor(ls0, 32, 64);
    ls1 += __shfl_xor(ls1, 16, 64); ls1 += __shfl_xor(ls1, 32, 64);
    ls2 += __shfl_xor(ls2, 16, 64); ls2 += __shfl_xor(ls2, 32, 64);
    ls3 += __shfl_xor(ls3, 16, 64); ls3 += __shfl_xor(ls3, 32, 64);
    float sel = ls0;
    if (qd == 1) sel = ls1;
    if (qd == 2) sel = ls2;
    if (qd == 3) sel = ls3;
    sL[w * 64 + lane] = sel;   // sL[w*64 + i] = denom of wave-local row i
    __syncthreads();           // BAR2: sL visible; qb reads of myW retired

    // ================= Phase 3: normalize O into wave scratch ==================
    short8 whf[2];
#pragma unroll
    for (int dt = 0; dt < 2; ++dt) {
        int n = dt * 16 + c;
        short8 f = {0,0,0,0,0,0,0,0};
        if (n < 20) {
#pragma unroll
            for (int j = 0; j < 8; ++j) {
                int k = qd * 8 + j;
                if (k < 20) f[j] = (short)bfhu(wh[(head * 20 + k) * 20 + n]);
            }
        }
        whf[dt] = f;
    }
#pragma unroll
    for (int mt = 0; mt < 4; ++mt) {
        float inv[4];
#pragma unroll
        for (int reg = 0; reg < 4; ++reg)
            inv[reg] = 1.f / (sL[w * 64 + mt * 16 + qd * 4 + reg] + 1e-10f);
#pragma unroll
        for (int dt = 0; dt < 2; ++dt) {
            int n = dt * 16 + c;
            if (n < 20) {
#pragma unroll
                for (int reg = 0; reg < 4; ++reg)
                    myW[(mt * 16 + qd * 4 + reg) * 24 + n] =
                        (short)bfhu(oacc[mt][dt][reg] * inv[reg]);
            }
        }
    }
    __syncthreads();   // BAR3: O writes visible before transposed read

    // ================= Phase 4: out-projection partial (own head) ==============
    f32x4 outacc[4][2];
#pragma unroll
    for (int mt = 0; mt < 4; ++mt) {
        short8 of = ldsA(myW, mt * 16 + c, qd);
        f32x4 z = {0.f, 0.f, 0.f, 0.f};
        outacc[mt][0] = MFMA32(of, whf[0], z);
        outacc[mt][1] = MFMA32(of, whf[1], z);
    }
    __syncthreads();   // BAR4: all sK/sVt/myW reads retired -> sOut overlay safe

    // ================= Phase 5: head1 writes f32 partials to sOut ==============
    if (head == 1) {
#pragma unroll
        for (int mt = 0; mt < 4; ++mt)
#pragma unroll
            for (int dt = 0; dt < 2; ++dt) {
                int n = dt * 16 + c;
                if (n < 20) {
#pragma unroll
                    for (int reg = 0; reg < 4; ++reg) {
                        int row = rowbase + mt * 16 + qd * 4 + reg;
                        sOut[row * 20 + n] = outacc[mt][dt][reg];
                    }
                }
            }
    }
    __syncthreads();   // BAR5: partials visible

    // ================= Phase 6: head0 combines + stores ========================
    if (head == 0) {
        float* ob = out + (size_t)b * (SEQL * DH);
#pragma unroll
        for (int mt = 0; mt < 4; ++mt)
#pragma unroll
            for (int dt = 0; dt < 2; ++dt) {
                int n = dt * 16 + c;
                if (n < 20) {
#pragma unroll
                    for (int reg = 0; reg < 4; ++reg) {
                        int row = rowbase + mt * 16 + qd * 4 + reg;
                        ob[row * 20 + n] = outacc[mt][dt][reg] + sOut[row * 20 + n];
                    }
                }
            }
    }
}

extern "C" void kernel_launch(void* const* d_in, const int* in_sizes, int n_in,
                              void* d_out, int out_size, void* d_ws, size_t ws_size,
                              hipStream_t stream) {
    const float* x  = (const float*)d_in[0];
    const float* y  = (const float*)d_in[1];
    const float* wq = (const float*)d_in[2];
    const float* wk = (const float*)d_in[3];
    const float* wv = (const float*)d_in[4];
    const float* wh = (const float*)d_in[5];
    float* out = (float*)d_out;

    set_attn_v10<<<dim3(NSET * NSET), dim3(512), 0, stream>>>(x, y, wq, wk, wv, wh, out);
}